// Round 11
// baseline (134.425 us; speedup 1.0000x reference)
//
#include <hip/hip_runtime.h>

#define TPB 256
#define R 8           // source points per lane
#define CHUNKS 64     // CH = N/CHUNKS = 256 targets per block
#define CH 256
constexpr int N = 16384;
// SB = N/(TPB*R) = 8 source-blocks/dir; grid = 2*SB*CHUNKS = 1024 blocks = 4/CU

// Pack {x,y,z,|p|^2}; init pmins = 0xFFFFFFFF (uint-max), cnt = 0.
__global__ __launch_bounds__(TPB) void prep_kernel(
        const float* __restrict__ a, const float* __restrict__ b,
        float4* __restrict__ pa, float4* __restrict__ pb,
        unsigned* __restrict__ pmins, unsigned* __restrict__ cnt) {
    int idx = blockIdx.x * blockDim.x + threadIdx.x;
    if (idx < N) {
        float x = a[3 * idx], y = a[3 * idx + 1], z = a[3 * idx + 2];
        pa[idx] = make_float4(x, y, z, x * x + y * y + z * z);
    } else if (idx < 2 * N) {
        int i = idx - N;
        float x = b[3 * i], y = b[3 * i + 1], z = b[3 * i + 2];
        pb[i] = make_float4(x, y, z, x * x + y * y + z * z);
    }
    if (idx < 2 * N) pmins[idx] = 0xFFFFFFFFu;
    if (idx == 0) cnt[0] = 0u;
}

// min_t(|s-t|^2) = |s|^2 + min_t(|t|^2 - 2 s.t)
// Lane L reads tile[(j+L)&63] — distinct addresses (conflict-free 12-cyc
// ds_read_b128) instead of the same-address wave broadcast, which measures
// ~27 cyc (no HW dedup for wide reads -> serializes like a bank conflict).
// Rotation is a permutation: over 64 steps every lane sees every target.
__global__ __launch_bounds__(TPB, 4) void minpass_kernel(
        const float4* __restrict__ pa, const float4* __restrict__ pb,
        unsigned* __restrict__ pmins, unsigned* __restrict__ cnt,
        float* __restrict__ out, int nblocks) {
    const int SB = N / (TPB * R);   // 8
    int b = blockIdx.x;
    int dir = b / (SB * CHUNKS);
    int rem = b % (SB * CHUNKS);
    int chunk = rem / SB;
    int sblk = rem % SB;
    const float4* __restrict__ src = dir ? pb : pa;
    const float4* __restrict__ tgt = dir ? pa : pb;

    __shared__ float4 tile[CH];  // 4 KB
    int base = chunk * CH;
    for (int i = threadIdx.x; i < CH; i += TPB)
        tile[i] = tgt[base + i];

    float ax[R], ay[R], az[R], sw[R], m[R];
    int s0 = sblk * TPB * R + threadIdx.x;  // stride-TPB between r's: coalesced
#pragma unroll
    for (int r = 0; r < R; ++r) {
        float4 s = src[s0 + r * TPB];
        ax[r] = -2.0f * s.x; ay[r] = -2.0f * s.y; az[r] = -2.0f * s.z;
        sw[r] = s.w; m[r] = __builtin_inff();
    }
    __syncthreads();

    int lane = threadIdx.x & 63;
#pragma unroll 1
    for (int g = 0; g < CH / 64; ++g) {
        const float4* tg = &tile[g * 64];
#pragma unroll 4
        for (int j = 0; j < 64; j += 2) {
            float4 p0 = tg[(j + lane) & 63];      // rotated: conflict-free
            float4 p1 = tg[(j + 1 + lane) & 63];
#pragma unroll
            for (int r = 0; r < R; ++r) {
                float d0 = fmaf(ax[r], p0.x, fmaf(ay[r], p0.y, fmaf(az[r], p0.z, p0.w)));
                float d1 = fmaf(ax[r], p1.x, fmaf(ay[r], p1.y, fmaf(az[r], p1.z, p1.w)));
                m[r] = fminf(m[r], fminf(d0, d1));  // -> v_min3_f32
            }
        }
    }

    // nonneg floats monotone under unsigned compare -> uint atomicMin
#pragma unroll
    for (int r = 0; r < R; ++r)
        atomicMin(&pmins[dir * N + s0 + r * TPB], __float_as_uint(m[r] + sw[r]));

    // --- counter-gated finalize: last block sums all 2N mins ---
    __syncthreads();   // compiler drains vmcnt before barrier: mins complete
    __shared__ int last;
    if (threadIdx.x == 0) {
        __threadfence();
        last = (atomicAdd(cnt, 1u) == (unsigned)(nblocks - 1)) ? 1 : 0;
    }
    __syncthreads();
    if (last) {
        __threadfence();
        float sum = 0.0f;
        for (int i = threadIdx.x; i < 2 * N; i += TPB) {
            unsigned u = __hip_atomic_load(&pmins[i], __ATOMIC_RELAXED,
                                           __HIP_MEMORY_SCOPE_AGENT);
            sum += __uint_as_float(u);
        }
        for (int off = 32; off > 0; off >>= 1)
            sum += __shfl_down(sum, off, 64);
        __shared__ float wsum[TPB / 64];
        int wid = threadIdx.x >> 6;
        if ((threadIdx.x & 63) == 0) wsum[wid] = sum;
        __syncthreads();
        if (threadIdx.x == 0) {
            float t = 0.0f;
            for (int w = 0; w < TPB / 64; ++w) t += wsum[w];
            out[0] = t / (float)(2 * N);
        }
    }
}

extern "C" void kernel_launch(void* const* d_in, const int* in_sizes, int n_in,
                              void* d_out, int out_size, void* d_ws, size_t ws_size,
                              hipStream_t stream) {
    const float* a = (const float*)d_in[0];
    const float* b = (const float*)d_in[1];
    float* out = (float*)d_out;
    char* ws = (char*)d_ws;
    unsigned* cnt = (unsigned*)ws;           // 1 uint
    float4* pa = (float4*)(ws + 256);        // N float4
    float4* pb = pa + N;                     // N float4
    unsigned* pmins = (unsigned*)(ws + 256 + 2 * (size_t)N * sizeof(float4));

    prep_kernel<<<(2 * N + TPB - 1) / TPB, TPB, 0, stream>>>(a, b, pa, pb, pmins, cnt);
    int SB = N / (TPB * R);
    int nblocks = 2 * SB * CHUNKS;  // 1024
    minpass_kernel<<<nblocks, TPB, 0, stream>>>(pa, pb, pmins, cnt, out, nblocks);
}